// Round 1
// 276.922 us; speedup vs baseline: 1.0123x; 1.0123x over previous
//
#include <hip/hip_runtime.h>
#include <stdint.h>

// DilateAttention: B=16, C=384 (12 heads x 32), H=W=56, 3x3 window, dil=2,
// reflect pad. Memory-bound; ideal HBM ~308 MB.
//
// R4: counted-vmcnt software pipeline (T3/T4). R3 post-mortem: VALUBusy 7%,
// HBM 26%, occupancy 33% -> latency-bound on the __syncthreads() vmcnt(0)
// drain, which serialized every chunk's staging behind its own barrier.
// New structure:
//   * 512 thr = 8 waves; wave wv handles band row wv AND staging slice wv
//     -> exactly 3 global_load_lds instrs per wave per chunk (exact ledger).
//   * raw s_barrier + counted s_waitcnt vmcnt(N); staging for chunk c+1/c+2
//     stays in flight across compute. Two barriers per step (buffer reuse).
//   * q register-prefetched one chunk ahead (must be issued BEFORE the next
//     stage so the compiler's q-wait doesn't drain the staging queue).
// VMEM ledger per wave (vmcnt retires in issue order):
//   pass1 step top: [s(c)x3, q(c)x8, s(c+1)x3] -> vmcnt(11)
//   pass2 step top: p=0:[s4,s5]->3  p=1:[s5,st0,s6]->5
//                   p=2:[st0,s6,st1,s7]->5  p=3:[st1,s7,st2... ]->2
// blocks = 16*12*7 = 1344, 512 thr, LDS 43008 B -> 3 blk/CU, 24 waves/CU.

#define BB 16
#define CH 384
#define HH 56
#define WW 56
#define NH 12
#define DD 32
#define HW (HH * WW)
#define KSQ 9
#define SCALE 0.17677669529663687f  // 32^-0.5

#define BAND 8                 // pixel rows per block
#define DCH 8                  // d-channels per staged chunk
#define NCHUNK (DD / DCH)      // 4
#define MAXROWS 12             // band + 2*halo
#define SLICE (MAXROWS * WW)   // floats per d-slice in LDS (672)
#define LBUF (DCH * SLICE)     // floats per buffer (5376)

#define WAITV(n) asm volatile("s_waitcnt vmcnt(" #n ")" ::: "memory")
#define FENCE()  asm volatile("" ::: "memory")
#define BAR()    do { FENCE(); __builtin_amdgcn_s_barrier(); FENCE(); } while (0)

__device__ __forceinline__ void async16(const void* g, void* l) {
    __builtin_amdgcn_global_load_lds(
        (const __attribute__((address_space(1))) void*)g,
        (__attribute__((address_space(3))) void*)l, 16, 0, 0);
}

// Stage one d-chunk: wave wv stages d-slice wv (nr rows x 56 cols).
// Exactly 3 x 1KB wave-instrs: offsets 0, 1024, Sbytes-1024 (third overlaps
// second; duplicate writes carry identical data). 16B alignment holds:
// planebase*4, lo*224, Sbytes-1024 are all multiples of 16.
__device__ __forceinline__ void stage_chunk(const float* __restrict__ plane0,
                                            float* ldsbuf, int Sbytes,
                                            int wv, int lane) {
    const int lo16 = lane * 16;
    const char* g = (const char*)(plane0 + wv * HW);
    char* l = (char*)(ldsbuf + wv * SLICE);
    async16(g + lo16, l + lo16);
    async16(g + 1024 + lo16, l + 1024 + lo16);
    const int t = Sbytes - 1024;
    async16(g + t + lo16, l + t + lo16);
}

__global__ __launch_bounds__(512, 6)
void dilate_attn_kernel(const float* __restrict__ q,
                        const float* __restrict__ k,
                        const float* __restrict__ v,
                        float* __restrict__ out) {
    __shared__ __align__(16) float lds[2][LBUF];  // 43008 B

    const int band = blockIdx.x;       // 0..6
    const int n    = blockIdx.y;       // head
    const int b    = blockIdx.z;

    const int tid  = threadIdx.x;      // 0..511
    const int lane = tid & 63;
    const int wv   = tid >> 6;         // 0..7: band row AND staging slice

    const bool act = lane < WW;        // lanes 56..63 idle in compute/store
    const int w  = act ? lane : (WW - 1);
    const int h0 = band * BAND;
    const int h  = h0 + wv;

    // staged (clamped, contiguous) row range
    const int lo = (h0 - 2 < 0) ? 0 : h0 - 2;
    const int hi = (h0 + 9 > HH - 1) ? HH - 1 : h0 + 9;
    const int Sbytes = (hi - lo + 1) * WW * 4;   // 2240 or 2688

    // 9 window offsets inside an LDS d-slice (reflected rows/cols)
    int off9[KSQ];
    {
        int wc[3];
#pragma unroll
        for (int j = 0; j < 3; ++j) {
            int c = w + 2 * (j - 1);
            c = (c < 0) ? -c : ((c >= WW) ? (2 * WW - 2 - c) : c);
            wc[j] = c;
        }
#pragma unroll
        for (int i = 0; i < 3; ++i) {
            int rr = h + 2 * (i - 1);
            rr = (rr < 0) ? -rr : ((rr >= HH) ? (2 * HH - 2 - rr) : rr);
            rr -= lo;                  // LDS row index, in [0, nr)
#pragma unroll
            for (int j = 0; j < 3; ++j) off9[i * 3 + j] = rr * WW + wc[j];
        }
    }

    const int planebase = (b * CH + n * DD) * HW;     // first d-plane of head
    const float* qp = q + planebase + h * WW + w;
    const float* kstage = k + planebase + lo * WW;
    const float* vstage = v + planebase + lo * WW;

    float sc[KSQ];
#pragma unroll
    for (int ii = 0; ii < KSQ; ++ii) sc[ii] = 0.f;

    // ---- prologue: issue s0, q0, s1 -> queue [s0 x3, q0 x8, s1 x3] ----
    stage_chunk(kstage, lds[0], Sbytes, wv, lane);
    FENCE();
    float qd[DCH];
#pragma unroll
    for (int j = 0; j < DCH; ++j) qd[j] = qp[j * HW];
    FENCE();
    stage_chunk(kstage + DCH * HW, lds[1], Sbytes, wv, lane);
    FENCE();

    // ---------------- pass 1: scores over 4 k-chunks ----------------
#pragma unroll
    for (int c = 0; c < NCHUNK; ++c) {
        WAITV(11);            // drain s(c); leave [q(c) x8, s(c+1) x3] in flight
        BAR();                // buf[c&1] now valid in every wave
        float qn[DCH];
        if (c < NCHUNK - 1) { // q prefetch for c+1 (issued BEFORE next stage)
#pragma unroll
            for (int j = 0; j < DCH; ++j) qn[j] = qp[((c + 1) * DCH + j) * HW];
        }
        const float* Bf = lds[c & 1];
#pragma unroll
        for (int j = 0; j < DCH; ++j) {
            const float* Ls = Bf + j * SLICE;
            const float qj = qd[j];
#pragma unroll
            for (int ii = 0; ii < KSQ; ++ii)
                sc[ii] = fmaf(qj, Ls[off9[ii]], sc[ii]);
        }
        if (c < NCHUNK - 1) {
#pragma unroll
            for (int j = 0; j < DCH; ++j) qd[j] = qn[j];
        }
        BAR();                // all waves done reading buf[c&1]
        // stage chunk c+2 into buf[c&1]: chunks 2,3 = k; 4,5 = v0,v1
        const float* src = (c + 2 < NCHUNK)
                               ? (kstage + (c + 2) * DCH * HW)
                               : (vstage + (c + 2 - NCHUNK) * DCH * HW);
        stage_chunk(src, lds[c & 1], Sbytes, wv, lane);
        FENCE();
    }

    // ---------------- softmax over the 9 positions ----------------
    {
        float m = sc[0];
#pragma unroll
        for (int ii = 1; ii < KSQ; ++ii) m = fmaxf(m, sc[ii]);
        float sum = 0.f;
#pragma unroll
        for (int ii = 0; ii < KSQ; ++ii) {
            sc[ii] = __expf((sc[ii] - m) * SCALE);
            sum += sc[ii];
        }
        const float inv = 1.f / sum;
#pragma unroll
        for (int ii = 0; ii < KSQ; ++ii) sc[ii] *= inv;
    }

    // ---------------- pass 2: output over 4 v-chunks ----------------
    float* op = out + ((b * HH + h) * WW + w) * CH + n * DD;

#pragma unroll
    for (int p = 0; p < NCHUNK; ++p) {
        // ledger: p=0 [s4x3,s5x3]->3 ; p=1 [s5x3,st0x2,s6x3]->5 ;
        //         p=2 [st0x2,s6x3,st1x2,s7x3]->5 ; p=3 [st1x2,s7x3,st2x2]->2
        if (p == 0)      WAITV(3);
        else if (p == 3) WAITV(2);
        else             WAITV(5);
        BAR();
        const float* Bf = lds[p & 1];      // chunk 4+p lives in buf[p&1]
        float o[DCH];
#pragma unroll
        for (int j = 0; j < DCH; ++j) {
            const float* Ls = Bf + j * SLICE;
            float acc = 0.f;
#pragma unroll
            for (int ii = 0; ii < KSQ; ++ii)
                acc = fmaf(sc[ii], Ls[off9[ii]], acc);
            o[j] = acc;
        }
        if (act) {
            *(float4*)(op + p * DCH)     = make_float4(o[0], o[1], o[2], o[3]);
            *(float4*)(op + p * DCH + 4) = make_float4(o[4], o[5], o[6], o[7]);
        }
        if (p < 2) {
            BAR();            // all waves done reading buf[p&1]
            stage_chunk(vstage + (p + 2) * DCH * HW, lds[p & 1], Sbytes, wv, lane);
            FENCE();
        }
    }
}

extern "C" void kernel_launch(void* const* d_in, const int* in_sizes, int n_in,
                              void* d_out, int out_size, void* d_ws, size_t ws_size,
                              hipStream_t stream) {
    const float* q = (const float*)d_in[0];
    const float* k = (const float*)d_in[1];
    const float* v = (const float*)d_in[2];
    float* out = (float*)d_out;

    dim3 grid(HH / BAND, NH, BB);   // 7 x 12 x 16 = 1344 blocks
    dilate_attn_kernel<<<grid, 512, 0, stream>>>(q, k, v, out);
}